// Round 10
// baseline (1395.782 us; speedup 1.0000x reference)
//
#include <hip/hip_runtime.h>
#include <math.h>

#define BATCH 512
#define SEQ   200
#define TOK   10
#define EMB   25
#define HID   64
#define G3    192   // 3*HID
#define ATILE 8     // attn phase-1 s-tile
#define EMB_BLOCKS ((BATCH * SEQ) / 8)   // 12800
#define RPK_BLOCKS 96                    // U repack: 12 slices x 8 sub-blocks

__device__ __forceinline__ float fast_sigmoid(float t) {
    float e = __expf(-t);
    return __builtin_amdgcn_rcpf(1.f + e);
}
__device__ __forceinline__ float fast_tanh(float t) {
    float e2 = __expf(2.f * t);
    return 1.f - 2.f * __builtin_amdgcn_rcpf(e2 + 1.f);
}

// Barrier that orders LDS producer->consumer WITHOUT draining vmcnt.
#define LDS_BARRIER() do {                                   \
    asm volatile("s_waitcnt lgkmcnt(0)" ::: "memory");       \
    __builtin_amdgcn_s_barrier();                            \
    asm volatile("" ::: "memory");                           \
} while (0)

// ---------------------------------------------------------------------------
// Kernel 1: masked-mean embedding bag + step mask. Trailing 96 blocks repack
// U into LANE-CONTIGUOUS per-(dir,gate,khalf) slices:
//   ut3[slice*2048 + j*32 + k] = U[(kh*32+k)*G3 + g*64 + j]
// so a GRU lane streams its 32 weights as 8 dwordx4 loads off ONE address
// register with immediate offsets 0..112B (zero per-step address math).
// ---------------------------------------------------------------------------
__global__ __launch_bounds__(256) void emb_mean_kernel(
    const int* __restrict__ ids_g, const float* __restrict__ emb,
    const float* __restrict__ U_f, const float* __restrict__ U_b,
    float* __restrict__ x, float* __restrict__ mask, float* __restrict__ ut3)
{
    if (blockIdx.x >= EMB_BLOCKS) {
        const int eb = blockIdx.x - EMB_BLOCKS;   // 0..95
        const int slice = eb >> 3, sub = eb & 7;
        const int dir = slice / 6, rem = slice % 6;
        const int g = rem >> 1, kh = rem & 1;
        const int idx = sub * 256 + threadIdx.x;  // 0..2047 over 8 sub-blocks
        const int jj = idx >> 5, k = idx & 31;
        const float* U = dir ? U_b : U_f;
        ut3[(size_t)slice * 2048 + idx] =
            U[(size_t)(kh * 32 + k) * G3 + g * HID + jj];
        return;
    }
    int grp  = blockIdx.x * 8 + (threadIdx.x >> 5);
    int lane = threadIdx.x & 31;
    const int* ids = ids_g + (size_t)grp * TOK;
    float acc = 0.f;
    int cnt = 0;
    #pragma unroll
    for (int t = 0; t < TOK; t++) {
        int id = ids[t];
        if (id != 0) {
            cnt++;
            if (lane < EMB) acc += emb[(size_t)id * EMB + lane];
        }
    }
    if (lane < EMB)
        x[(size_t)grp * EMB + lane] = cnt ? acc / (float)cnt : 0.f;
    if (lane == 0)
        mask[grp] = (ids[0] != 0) ? 1.f : 0.f;
}

// ---------------------------------------------------------------------------
// Kernel 1b: x-projection hoisted OUT of the scan (unchanged from r9).
//   xp[(dir*102400 + b*200 + s)*192 + cc] = b_dir[0][cc] + x[b,s,:]@W_dir[:,cc]
// ---------------------------------------------------------------------------
__global__ __launch_bounds__(384) void xproj_kernel(
    const float* __restrict__ xg,
    const float* __restrict__ W_f, const float* __restrict__ b_f,
    const float* __restrict__ W_b, const float* __restrict__ b_b,
    float* __restrict__ xp)
{
    const int t   = threadIdx.x;          // 0..383
    const int dir = t / G3, cc = t - dir * G3;
    const int gr0 = blockIdx.x * 64;      // first global row (b*200+s)

    __shared__ __align__(16) float xsr[64][28];
    for (int i = t; i < 64 * 28; i += 384) {
        int r = i / 28, e = i - r * 28;
        xsr[r][e] = (e < EMB) ? xg[(size_t)(gr0 + r) * EMB + e] : 0.f;
    }

    const float* W  = dir ? W_b : W_f;
    const float* bb = dir ? b_b : b_f;
    float wreg[28];
    #pragma unroll
    for (int e = 0; e < EMB; e++) wreg[e] = W[(size_t)e * G3 + cc];
    #pragma unroll
    for (int e = EMB; e < 28; e++) wreg[e] = 0.f;
    const float bias = bb[cc];

    __syncthreads();

    float* op = xp + ((size_t)(dir * (BATCH * SEQ) + gr0)) * G3 + cc;
    #pragma unroll 4
    for (int r = 0; r < 64; r++) {
        const float4* xv4 = (const float4*)xsr[r];
        float a0 = bias, a1 = 0.f;
        #pragma unroll
        for (int c = 0; c < 7; c++) {
            const float4 xv = xv4[c];
            a0 = fmaf(xv.x, wreg[4 * c + 0], a0);
            a1 = fmaf(xv.y, wreg[4 * c + 1], a1);
            a0 = fmaf(xv.z, wreg[4 * c + 2], a0);
            a1 = fmaf(xv.w, wreg[4 * c + 3], a1);
        }
        op[(size_t)r * G3] = a0 + a1;
    }
}

// ---------------------------------------------------------------------------
// Kernel 2: GRU scan v6 — r9 skeleton (6 waves = gate x khalf, ONE barrier
// per step, redundant combine, wave-private h), issue-count stripped:
//  - lane-contiguous ut3: 8 dwordx4 off one pinned address reg with
//    immediate offsets -> weight reload costs 8 bare issues, 0 VALU
//    (the allocator WILL reload in-loop — 6 rounds of evidence — so make
//    reloading free instead of fighting for residency).
//  - pointer-walk xp stream, prefetch depth 2, no clamp (xp has guard
//    rows on both sides by construction).
//  - chan[2][7][72]: +8-pad kills the stride-64 bank conflicts (r9: 160K).
//  - pointer-walk out stores.
// ---------------------------------------------------------------------------

#define RECC(c) { const float4 hv = hv4[c];              \
    a0 = fmaf(hv.x, u##c.x, a0);                         \
    a1 = fmaf(hv.y, u##c.y, a1);                         \
    a0 = fmaf(hv.z, u##c.z, a0);                         \
    a1 = fmaf(hv.w, u##c.w, a1); }

__global__ __launch_bounds__(384, 2) void gru_kernel(
    const float* __restrict__ xp, const float* __restrict__ maskg,
    const float* __restrict__ b_f, const float* __restrict__ b_b,
    const float* __restrict__ ut3,
    float* __restrict__ outg, float* __restrict__ hT)
{
    const int bid = blockIdx.x;
    const int dir = bid >> 9;          // 0 = forward, 1 = backward
    const int b   = bid & 511;
    const int tid = threadIdx.x;
    const int w   = tid >> 6;          // wave 0..5
    const int j   = tid & 63;          // hidden column
    const int g   = w >> 1;            // gate: 0=z 1=r 2=h
    const int kh  = w & 1;             // k-half
    const int slice = (dir * 3 + g) * 2 + kh;
    const int row   = (g < 2) ? (g * 2 + kh) : (4 + kh);
    const bool hxw  = (g == 2 && kh == 0);

    __shared__ float ms[SEQ];
    __shared__ __align__(16) float hsw[6][HID];    // per-wave private h
    __shared__ float chan[2][7][72];               // parity dbuf, +8 pad

    if (tid < SEQ) ms[tid] = maskg[(size_t)b * SEQ + tid];
    hsw[w][j] = 0.f;

    const float* bias = dir ? b_b : b_f;
    const float b1 = (kh == 0) ? bias[G3 + g * HID + j] : 0.f;  // rec bias

    __syncthreads();   // staging barrier (once)

    // lane-contiguous weight base: ONE address, immediate offsets in-loop
    const float* ubase = ut3 + (size_t)slice * 2048 + (j << 5);

    // xp stream (kh0 waves), pointer-walk, prefetch depth 2, no clamp
    const int sd = dir ? -1 : 1;
    const int pstride = sd * G3;
    int s = dir ? (SEQ - 1) : 0;
    const float* xpp = xp + ((size_t)(dir * (BATCH * SEQ) + b * SEQ + s)) * G3
                          + g * HID + j;
    float x0 = 0.f, x1 = 0.f;
    if (kh == 0) {
        x0 = xpp[0];
        x1 = xpp[pstride];
    }

    float h = 0.f;
    float* ob = outg + (size_t)b * SEQ * (2 * HID) + (size_t)s * (2 * HID)
                     + dir * HID + j;
    const int obstride = sd * (2 * HID);
    int p = 0;

    for (int step = 0; step < SEQ; step++) {
        float* chp = &chan[p][0][0];

        // weight stream: 8 dwordx4, pinned base, immediate offsets
        const float* up = ubase;
        asm volatile("" : "+v"(up));
        const float4 u0 = *(const float4*)(up + 0);
        const float4 u1 = *(const float4*)(up + 4);
        const float4 u2 = *(const float4*)(up + 8);
        const float4 u3 = *(const float4*)(up + 12);
        const float4 u4 = *(const float4*)(up + 16);
        const float4 u5 = *(const float4*)(up + 20);
        const float4 u6 = *(const float4*)(up + 24);
        const float4 u7 = *(const float4*)(up + 28);

        // recurrent partial from OWN private h copy (broadcast b128 reads)
        const float4* hv4 = (const float4*)&hsw[w][kh * 32];
        float a0 = 0.f, a1 = 0.f;
        RECC(0) RECC(1) RECC(2) RECC(3) RECC(4) RECC(5) RECC(6) RECC(7)
        float part = a0 + a1;
        if (kh == 0) part += b1 + ((g < 2) ? x0 : 0.f);  // z/r merge xp here
        chp[row * 72 + j] = part;
        if (hxw) chp[6 * 72 + j] = x0;                   // xh kept separate

        // prefetch xp two steps ahead (in-bounds by guard construction)
        float x2 = 0.f;
        if (kh == 0) x2 = xpp[2 * pstride];

        LDS_BARRIER();   // the ONLY barrier per step

        // redundant combine: every wave, identical result (lockstep fp)
        {
            float z  = fast_sigmoid(chp[0 * 72 + j] + chp[1 * 72 + j]);
            float r  = fast_sigmoid(chp[2 * 72 + j] + chp[3 * 72 + j]);
            float rh =              chp[4 * 72 + j] + chp[5 * 72 + j];
            float hh = fast_tanh(chp[6 * 72 + j] + r * rh);
            float hn = z * h + (1.f - z) * hh;
            hn = (ms[s] != 0.f) ? hn : h;
            h = hn;
            hsw[w][j] = hn;                       // own private copy
            if (w == 0) *ob = hn;                 // fire-and-forget
        }

        x0 = x1; x1 = x2;
        xpp += pstride;
        ob  += obstride;
        s += sd;
        p ^= 1;
    }
    if (w == 0 && dir == 0) hT[(size_t)b * HID + j] = h;
}

// ---------------------------------------------------------------------------
// Kernel 3: attention pooling v2 (unchanged from round 6).
// ---------------------------------------------------------------------------

#define WK_LIST(M) \
  M(0)  M(1)  M(2)  M(3)  M(4)  M(5)  M(6)  M(7)  \
  M(8)  M(9)  M(10) M(11) M(12) M(13) M(14) M(15) \
  M(16) M(17) M(18) M(19) M(20) M(21) M(22) M(23) \
  M(24) M(25) M(26) M(27) M(28) M(29) M(30) M(31)

#define DECL_WK(t) const float wk##t = W_k[(size_t)(32 * wave + (t)) * HID + lane];

#define KF4(q, t0, t1, t2, t3) {                  \
    const float4 ov = o4[q];                      \
    acc0 = fmaf(ov.x, wk##t0, acc0);              \
    acc1 = fmaf(ov.y, wk##t1, acc1);              \
    acc0 = fmaf(ov.z, wk##t2, acc0);              \
    acc1 = fmaf(ov.w, wk##t3, acc1); }

__global__ __launch_bounds__(256) void attn_kernel(
    const float* __restrict__ outg, const float* __restrict__ maskg,
    const float* __restrict__ hT,
    const float* __restrict__ W_k, const float* __restrict__ b_k,
    const float* __restrict__ W_q, const float* __restrict__ b_q,
    const float* __restrict__ W_e, const float* __restrict__ b_e,
    float* __restrict__ ctx)
{
    const int b    = blockIdx.x;
    const int tid  = threadIdx.x;
    const int wave = tid >> 6;
    const int lane = tid & 63;

    __shared__ float qs[HID];
    __shared__ float es[SEQ];
    __shared__ __align__(16) float kp[ATILE][4][HID];
    __shared__ __align__(16) float psum[4][2 * HID];

    WK_LIST(DECL_WK)

    const float bkj = b_k[lane];
    const float wej = W_e[lane];
    const float be  = b_e[0];

    if (tid < HID) {
        float q = b_q[tid];
        const float* hrow = hT + (size_t)b * HID;
        #pragma unroll 8
        for (int i = 0; i < HID; i++) q = fmaf(hrow[i], W_q[i * HID + tid], q);
        qs[tid] = q;
    }
    __syncthreads();
    const float qj = qs[lane];

    for (int s0 = 0; s0 < SEQ; s0 += ATILE) {
        #pragma unroll 2
        for (int t = 0; t < ATILE; t++) {
            const int s = s0 + t;
            const float4* o4 = (const float4*)(outg +
                ((size_t)b * SEQ + s) * (2 * HID) + 32 * wave);
            float acc0 = 0.f, acc1 = 0.f;
            KF4(0,  0,  1,  2,  3)  KF4(1,  4,  5,  6,  7)
            KF4(2,  8,  9, 10, 11)  KF4(3, 12, 13, 14, 15)
            KF4(4, 16, 17, 18, 19)  KF4(5, 20, 21, 22, 23)
            KF4(6, 24, 25, 26, 27)  KF4(7, 28, 29, 30, 31)
            kp[t][wave][lane] = acc0 + acc1;
        }
        __syncthreads();
        #pragma unroll
        for (int t = wave; t < ATILE; t += 4) {
            const int s = s0 + t;
            float k = (kp[t][0][lane] + kp[t][1][lane]) +
                      (kp[t][2][lane] + kp[t][3][lane]);
            float v = tanhf(k + bkj + qj) * wej;
            #pragma unroll
            for (int off = 32; off > 0; off >>= 1) v += __shfl_xor(v, off);
            if (lane == 0) {
                float pen = (maskg[(size_t)b * SEQ + s] != 0.f) ? 0.f : -1e9f;
                es[s] = v + be + pen;
            }
        }
        __syncthreads();
    }

    if (tid < 64) {
        float mx = -1e30f;
        for (int s2 = tid; s2 < SEQ; s2 += 64) mx = fmaxf(mx, es[s2]);
        #pragma unroll
        for (int off = 32; off > 0; off >>= 1) mx = fmaxf(mx, __shfl_xor(mx, off));
        float sum = 0.f;
        for (int s2 = tid; s2 < SEQ; s2 += 64) {
            float w = expf(es[s2] - mx);
            es[s2] = w;
            sum += w;
        }
        #pragma unroll
        for (int off = 32; off > 0; off >>= 1) sum += __shfl_xor(sum, off);
        float inv = 1.f / sum;
        for (int s2 = tid; s2 < SEQ; s2 += 64) es[s2] *= inv;
    }
    __syncthreads();

    {
        float a0 = 0.f, a1 = 0.f;
        #pragma unroll 2
        for (int s2 = wave; s2 < SEQ; s2 += 4) {
            const float2 v = *(const float2*)(outg +
                ((size_t)b * SEQ + s2) * (2 * HID) + lane * 2);
            const float wsc = es[s2];
            a0 = fmaf(wsc, v.x, a0);
            a1 = fmaf(wsc, v.y, a1);
        }
        psum[wave][2 * lane]     = a0;
        psum[wave][2 * lane + 1] = a1;
    }
    __syncthreads();
    if (tid < 2 * HID) {
        ctx[(size_t)b * (2 * HID) + tid] =
            (psum[0][tid] + psum[1][tid]) + (psum[2][tid] + psum[3][tid]);
    }
}

// ---------------------------------------------------------------------------
extern "C" void kernel_launch(void* const* d_in, const int* in_sizes, int n_in,
                              void* d_out, int out_size, void* d_ws, size_t ws_size,
                              hipStream_t stream) {
    const int*   ids = (const int*)  d_in[0];
    const float* emb = (const float*)d_in[1];
    const float* W_f = (const float*)d_in[2];
    const float* U_f = (const float*)d_in[3];
    const float* b_f = (const float*)d_in[4];
    const float* W_b = (const float*)d_in[5];
    const float* U_b = (const float*)d_in[6];
    const float* b_b = (const float*)d_in[7];
    const float* W_k = (const float*)d_in[8];
    const float* b_k = (const float*)d_in[9];
    const float* W_q = (const float*)d_in[10];
    const float* b_q = (const float*)d_in[11];
    const float* W_e = (const float*)d_in[12];
    const float* b_e = (const float*)d_in[13];

    float* ws   = (float*)d_ws;
    // workspace layout (floats):
    //   x    : [0, 2'560'000)                  (B*S*E)
    //   mask : [2'560'000, 2'662'400)          (B*S)
    //   out  : [2'662'400, 15'769'600)         (B*S*2H)
    //   hT   : [15'769'600, 15'802'368)        (B*H)
    //   ut3  : [15'802'368, 15'826'944)        (12 slices x 64 j x 32 k)
    //   xp   : [15'826'944, 55'148'544)        (2*B*S*192) = 157 MB
    float* x    = ws;
    float* mask = ws + 2560000;
    float* out  = ws + 2662400;
    float* hT   = ws + 15769600;
    float* ut3  = ws + 15802368;
    float* xp   = ws + 15826944;

    emb_mean_kernel<<<EMB_BLOCKS + RPK_BLOCKS, 256, 0, stream>>>(
        ids, emb, U_f, U_b, x, mask, ut3);
    xproj_kernel<<<(BATCH * SEQ) / 64, 384, 0, stream>>>(
        x, W_f, b_f, W_b, b_b, xp);
    gru_kernel<<<1024, 384, 0, stream>>>(xp, mask, b_f, b_b, ut3, out, hT);
    attn_kernel<<<BATCH, 256, 0, stream>>>(out, mask, hT, W_k, b_k,
                                           W_q, b_q, W_e, b_e, (float*)d_out);
}

// Round 11
// 475.296 us; speedup vs baseline: 2.9367x; 2.9367x over previous
//
#include <hip/hip_runtime.h>
#include <math.h>

#define BATCH 512
#define SEQ   200
#define TOK   10
#define EMB   25
#define HID   64
#define G3    192   // 3*HID
#define ATILE 8     // attn phase-1 s-tile
#define EMB_BLOCKS ((BATCH * SEQ) / 8)   // 12800
#define RPK_BLOCKS 96                    // U repack: 12 slices x 8 chunks

__device__ __forceinline__ float fast_sigmoid(float t) {
    float e = __expf(-t);
    return __builtin_amdgcn_rcpf(1.f + e);
}
__device__ __forceinline__ float fast_tanh(float t) {
    float e2 = __expf(2.f * t);
    return 1.f - 2.f * __builtin_amdgcn_rcpf(e2 + 1.f);
}

// Barrier that orders LDS producer->consumer WITHOUT draining vmcnt.
#define LDS_BARRIER() do {                                   \
    asm volatile("s_waitcnt lgkmcnt(0)" ::: "memory");       \
    __builtin_amdgcn_s_barrier();                            \
    asm volatile("" ::: "memory");                           \
} while (0)

// ---------------------------------------------------------------------------
// Kernel 1: masked-mean embedding bag + step mask. Trailing 96 blocks repack
// U into per-(dir,gate,khalf) COALESCED chunk-major slices (r9 layout —
// r10's lane-contiguous variant was a 128B-stride gather, 16x the VMEM
// transactions; reverted):
//   ut2[slice*2048 + c*256 + j*4 + q] = U[(kh*32+4c+q)*G3 + g*64 + j]
// A wave's chunk-c load: lane j reads 16B at +j*16 -> one coalesced 1KB line.
// ---------------------------------------------------------------------------
__global__ __launch_bounds__(256) void emb_mean_kernel(
    const int* __restrict__ ids_g, const float* __restrict__ emb,
    const float* __restrict__ U_f, const float* __restrict__ U_b,
    float* __restrict__ x, float* __restrict__ mask, float* __restrict__ ut2)
{
    if (blockIdx.x >= EMB_BLOCKS) {
        const int eb = blockIdx.x - EMB_BLOCKS;   // 0..95
        const int slice = eb >> 3, c = eb & 7;
        const int dir = slice / 6, rem = slice % 6;
        const int g = rem >> 1, kh = rem & 1;
        const int t = threadIdx.x;
        const int jj = t >> 2, q = t & 3;
        const float* U = dir ? U_b : U_f;
        ut2[(size_t)eb * 256 + t] =
            U[(size_t)(kh * 32 + 4 * c + q) * G3 + g * HID + jj];
        return;
    }
    int grp  = blockIdx.x * 8 + (threadIdx.x >> 5);
    int lane = threadIdx.x & 31;
    const int* ids = ids_g + (size_t)grp * TOK;
    float acc = 0.f;
    int cnt = 0;
    #pragma unroll
    for (int t = 0; t < TOK; t++) {
        int id = ids[t];
        if (id != 0) {
            cnt++;
            if (lane < EMB) acc += emb[(size_t)id * EMB + lane];
        }
    }
    if (lane < EMB)
        x[(size_t)grp * EMB + lane] = cnt ? acc / (float)cnt : 0.f;
    if (lane == 0)
        mask[grp] = (ids[0] != 0) ? 1.f : 0.f;
}

// ---------------------------------------------------------------------------
// Kernel 1b: x-projection hoisted OUT of the scan (unchanged from r9).
//   xp[(dir*102400 + b*200 + s)*192 + cc] = b_dir[0][cc] + x[b,s,:]@W_dir[:,cc]
// ---------------------------------------------------------------------------
__global__ __launch_bounds__(384) void xproj_kernel(
    const float* __restrict__ xg,
    const float* __restrict__ W_f, const float* __restrict__ b_f,
    const float* __restrict__ W_b, const float* __restrict__ b_b,
    float* __restrict__ xp)
{
    const int t   = threadIdx.x;          // 0..383
    const int dir = t / G3, cc = t - dir * G3;
    const int gr0 = blockIdx.x * 64;      // first global row (b*200+s)

    __shared__ __align__(16) float xsr[64][28];
    for (int i = t; i < 64 * 28; i += 384) {
        int r = i / 28, e = i - r * 28;
        xsr[r][e] = (e < EMB) ? xg[(size_t)(gr0 + r) * EMB + e] : 0.f;
    }

    const float* W  = dir ? W_b : W_f;
    const float* bb = dir ? b_b : b_f;
    float wreg[28];
    #pragma unroll
    for (int e = 0; e < EMB; e++) wreg[e] = W[(size_t)e * G3 + cc];
    #pragma unroll
    for (int e = EMB; e < 28; e++) wreg[e] = 0.f;
    const float bias = bb[cc];

    __syncthreads();

    float* op = xp + ((size_t)(dir * (BATCH * SEQ) + gr0)) * G3 + cc;
    #pragma unroll 4
    for (int r = 0; r < 64; r++) {
        const float4* xv4 = (const float4*)xsr[r];
        float a0 = bias, a1 = 0.f;
        #pragma unroll
        for (int c = 0; c < 7; c++) {
            const float4 xv = xv4[c];
            a0 = fmaf(xv.x, wreg[4 * c + 0], a0);
            a1 = fmaf(xv.y, wreg[4 * c + 1], a1);
            a0 = fmaf(xv.z, wreg[4 * c + 2], a0);
            a1 = fmaf(xv.w, wreg[4 * c + 3], a1);
        }
        op[(size_t)r * G3] = a0 + a1;
    }
}

// ---------------------------------------------------------------------------
// Kernel 2: GRU scan v7 — r9 skeleton (6 waves = gate x khalf, ONE barrier
// per step, redundant combine, wave-private h, hoisted xproj) with the
// weight slice preloaded via ONE INLINE-ASM BLOCK:
//   r10 proved the load-sink is not occupancy-driven (VGPR 36 at the same
//   8-wave tier) — it is default scheduler behavior for re-materializable
//   loads, immune to launch_bounds/waves_per_eu/pins. asm-defined values
//   are NOT re-materializable and CANNOT be sunk; at ~55-reg demand they
//   simply stay resident. In-loop weight cost: 16 FMAs, zero loads,
//   zero address math.
// ---------------------------------------------------------------------------

#define RECC(c) { const float4 hv = hv4[c];              \
    a0 = fmaf(hv.x, u##c.x, a0);                         \
    a1 = fmaf(hv.y, u##c.y, a1);                         \
    a0 = fmaf(hv.z, u##c.z, a0);                         \
    a1 = fmaf(hv.w, u##c.w, a1); }

__global__ __launch_bounds__(384, 2) void gru_kernel(
    const float* __restrict__ xp, const float* __restrict__ maskg,
    const float* __restrict__ b_f, const float* __restrict__ b_b,
    const float* __restrict__ ut2,
    float* __restrict__ outg, float* __restrict__ hT)
{
    const int bid = blockIdx.x;
    const int dir = bid >> 9;          // 0 = forward, 1 = backward
    const int b   = bid & 511;
    const int tid = threadIdx.x;
    const int w   = tid >> 6;          // wave 0..5
    const int j   = tid & 63;          // hidden column
    const int g   = w >> 1;            // gate: 0=z 1=r 2=h
    const int kh  = w & 1;             // k-half
    const int slice = (dir * 3 + g) * 2 + kh;
    const int row   = (g < 2) ? (g * 2 + kh) : (4 + kh);
    const bool hxw  = (g == 2 && kh == 0);

    __shared__ float ms[SEQ];
    __shared__ __align__(16) float hsw[6][HID];    // per-wave private h
    __shared__ float chan[2][7][HID];              // parity dbuf (r9: 0 conflicts)

    if (tid < SEQ) ms[tid] = maskg[(size_t)b * SEQ + tid];
    hsw[w][j] = 0.f;

    const float* bias = dir ? b_b : b_f;
    const float b1 = (kh == 0) ? bias[G3 + g * HID + j] : 0.f;  // rec bias

    // ---- weight preload: unsinkable asm block, 8 coalesced dwordx4 ----
    float4 u0, u1, u2, u3, u4, u5, u6, u7;
    {
        const float* ua = ut2 + (size_t)slice * 2048 + (j << 2);
        const float* ub2 = ua + 1024;   // +4096 B (chunks 4..7)
        asm volatile(
            "global_load_dwordx4 %0, %8, off\n\t"
            "global_load_dwordx4 %1, %8, off offset:1024\n\t"
            "global_load_dwordx4 %2, %8, off offset:2048\n\t"
            "global_load_dwordx4 %3, %8, off offset:3072\n\t"
            "global_load_dwordx4 %4, %9, off\n\t"
            "global_load_dwordx4 %5, %9, off offset:1024\n\t"
            "global_load_dwordx4 %6, %9, off offset:2048\n\t"
            "global_load_dwordx4 %7, %9, off offset:3072\n\t"
            "s_waitcnt vmcnt(0)"
            : "=&v"(u0), "=&v"(u1), "=&v"(u2), "=&v"(u3),
              "=&v"(u4), "=&v"(u5), "=&v"(u6), "=&v"(u7)
            : "v"(ua), "v"(ub2));
    }

    __syncthreads();   // staging barrier (once)

    // xp stream (kh0 waves), pointer-walk, prefetch depth 2.
    // Out-of-range prefetch rows (s=-2..-1, SEQ..SEQ+1) stay inside the xp
    // allocation by construction (adjacent b/dir rows); values are discarded.
    const int sd = dir ? -1 : 1;
    const int pstride = sd * G3;
    int s = dir ? (SEQ - 1) : 0;
    const float* xpp = xp + ((size_t)(dir * (BATCH * SEQ) + b * SEQ + s)) * G3
                          + g * HID + j;
    float x0 = 0.f, x1 = 0.f;
    if (kh == 0) {
        x0 = xpp[0];
        x1 = xpp[pstride];
    }

    float h = 0.f;
    float* ob = outg + (size_t)b * SEQ * (2 * HID) + (size_t)s * (2 * HID)
                     + dir * HID + j;
    const int obstride = sd * (2 * HID);
    int p = 0;

    for (int step = 0; step < SEQ; step++) {
        float* chp = &chan[p][0][0];

        // recurrent partial from OWN private h copy (broadcast b128 reads)
        const float4* hv4 = (const float4*)&hsw[w][kh * 32];
        float a0 = 0.f, a1 = 0.f;
        RECC(0) RECC(1) RECC(2) RECC(3) RECC(4) RECC(5) RECC(6) RECC(7)
        float part = a0 + a1;
        if (kh == 0) part += b1 + ((g < 2) ? x0 : 0.f);  // z/r merge xp here
        chp[row * HID + j] = part;
        if (hxw) chp[6 * HID + j] = x0;                  // xh kept separate

        // prefetch xp two steps ahead
        float x2 = 0.f;
        if (kh == 0) x2 = xpp[2 * pstride];

        LDS_BARRIER();   // the ONLY barrier per step

        // redundant combine: every wave, identical result (lockstep fp)
        {
            float z  = fast_sigmoid(chp[0 * HID + j] + chp[1 * HID + j]);
            float r  = fast_sigmoid(chp[2 * HID + j] + chp[3 * HID + j]);
            float rh =              chp[4 * HID + j] + chp[5 * HID + j];
            float hh = fast_tanh(chp[6 * HID + j] + r * rh);
            float hn = z * h + (1.f - z) * hh;
            hn = (ms[s] != 0.f) ? hn : h;
            h = hn;
            hsw[w][j] = hn;                       // own private copy
            if (w == 0) *ob = hn;                 // fire-and-forget
        }

        x0 = x1; x1 = x2;
        xpp += pstride;
        ob  += obstride;
        s += sd;
        p ^= 1;
    }
    if (w == 0 && dir == 0) hT[(size_t)b * HID + j] = h;
}

// ---------------------------------------------------------------------------
// Kernel 3: attention pooling v2 (unchanged from round 6).
// ---------------------------------------------------------------------------

#define WK_LIST(M) \
  M(0)  M(1)  M(2)  M(3)  M(4)  M(5)  M(6)  M(7)  \
  M(8)  M(9)  M(10) M(11) M(12) M(13) M(14) M(15) \
  M(16) M(17) M(18) M(19) M(20) M(21) M(22) M(23) \
  M(24) M(25) M(26) M(27) M(28) M(29) M(30) M(31)

#define DECL_WK(t) const float wk##t = W_k[(size_t)(32 * wave + (t)) * HID + lane];

#define KF4(q, t0, t1, t2, t3) {                  \
    const float4 ov = o4[q];                      \
    acc0 = fmaf(ov.x, wk##t0, acc0);              \
    acc1 = fmaf(ov.y, wk##t1, acc1);              \
    acc0 = fmaf(ov.z, wk##t2, acc0);              \
    acc1 = fmaf(ov.w, wk##t3, acc1); }

__global__ __launch_bounds__(256) void attn_kernel(
    const float* __restrict__ outg, const float* __restrict__ maskg,
    const float* __restrict__ hT,
    const float* __restrict__ W_k, const float* __restrict__ b_k,
    const float* __restrict__ W_q, const float* __restrict__ b_q,
    const float* __restrict__ W_e, const float* __restrict__ b_e,
    float* __restrict__ ctx)
{
    const int b    = blockIdx.x;
    const int tid  = threadIdx.x;
    const int wave = tid >> 6;
    const int lane = tid & 63;

    __shared__ float qs[HID];
    __shared__ float es[SEQ];
    __shared__ __align__(16) float kp[ATILE][4][HID];
    __shared__ __align__(16) float psum[4][2 * HID];

    WK_LIST(DECL_WK)

    const float bkj = b_k[lane];
    const float wej = W_e[lane];
    const float be  = b_e[0];

    if (tid < HID) {
        float q = b_q[tid];
        const float* hrow = hT + (size_t)b * HID;
        #pragma unroll 8
        for (int i = 0; i < HID; i++) q = fmaf(hrow[i], W_q[i * HID + tid], q);
        qs[tid] = q;
    }
    __syncthreads();
    const float qj = qs[lane];

    for (int s0 = 0; s0 < SEQ; s0 += ATILE) {
        #pragma unroll 2
        for (int t = 0; t < ATILE; t++) {
            const int s = s0 + t;
            const float4* o4 = (const float4*)(outg +
                ((size_t)b * SEQ + s) * (2 * HID) + 32 * wave);
            float acc0 = 0.f, acc1 = 0.f;
            KF4(0,  0,  1,  2,  3)  KF4(1,  4,  5,  6,  7)
            KF4(2,  8,  9, 10, 11)  KF4(3, 12, 13, 14, 15)
            KF4(4, 16, 17, 18, 19)  KF4(5, 20, 21, 22, 23)
            KF4(6, 24, 25, 26, 27)  KF4(7, 28, 29, 30, 31)
            kp[t][wave][lane] = acc0 + acc1;
        }
        __syncthreads();
        #pragma unroll
        for (int t = wave; t < ATILE; t += 4) {
            const int s = s0 + t;
            float k = (kp[t][0][lane] + kp[t][1][lane]) +
                      (kp[t][2][lane] + kp[t][3][lane]);
            float v = tanhf(k + bkj + qj) * wej;
            #pragma unroll
            for (int off = 32; off > 0; off >>= 1) v += __shfl_xor(v, off);
            if (lane == 0) {
                float pen = (maskg[(size_t)b * SEQ + s] != 0.f) ? 0.f : -1e9f;
                es[s] = v + be + pen;
            }
        }
        __syncthreads();
    }

    if (tid < 64) {
        float mx = -1e30f;
        for (int s2 = tid; s2 < SEQ; s2 += 64) mx = fmaxf(mx, es[s2]);
        #pragma unroll
        for (int off = 32; off > 0; off >>= 1) mx = fmaxf(mx, __shfl_xor(mx, off));
        float sum = 0.f;
        for (int s2 = tid; s2 < SEQ; s2 += 64) {
            float w = expf(es[s2] - mx);
            es[s2] = w;
            sum += w;
        }
        #pragma unroll
        for (int off = 32; off > 0; off >>= 1) sum += __shfl_xor(sum, off);
        float inv = 1.f / sum;
        for (int s2 = tid; s2 < SEQ; s2 += 64) es[s2] *= inv;
    }
    __syncthreads();

    {
        float a0 = 0.f, a1 = 0.f;
        #pragma unroll 2
        for (int s2 = wave; s2 < SEQ; s2 += 4) {
            const float2 v = *(const float2*)(outg +
                ((size_t)b * SEQ + s2) * (2 * HID) + lane * 2);
            const float wsc = es[s2];
            a0 = fmaf(wsc, v.x, a0);
            a1 = fmaf(wsc, v.y, a1);
        }
        psum[wave][2 * lane]     = a0;
        psum[wave][2 * lane + 1] = a1;
    }
    __syncthreads();
    if (tid < 2 * HID) {
        ctx[(size_t)b * (2 * HID) + tid] =
            (psum[0][tid] + psum[1][tid]) + (psum[2][tid] + psum[3][tid]);
    }
}

// ---------------------------------------------------------------------------
extern "C" void kernel_launch(void* const* d_in, const int* in_sizes, int n_in,
                              void* d_out, int out_size, void* d_ws, size_t ws_size,
                              hipStream_t stream) {
    const int*   ids = (const int*)  d_in[0];
    const float* emb = (const float*)d_in[1];
    const float* W_f = (const float*)d_in[2];
    const float* U_f = (const float*)d_in[3];
    const float* b_f = (const float*)d_in[4];
    const float* W_b = (const float*)d_in[5];
    const float* U_b = (const float*)d_in[6];
    const float* b_b = (const float*)d_in[7];
    const float* W_k = (const float*)d_in[8];
    const float* b_k = (const float*)d_in[9];
    const float* W_q = (const float*)d_in[10];
    const float* b_q = (const float*)d_in[11];
    const float* W_e = (const float*)d_in[12];
    const float* b_e = (const float*)d_in[13];

    float* ws   = (float*)d_ws;
    // workspace layout (floats):
    //   x    : [0, 2'560'000)                  (B*S*E)
    //   mask : [2'560'000, 2'662'400)          (B*S)
    //   out  : [2'662'400, 15'769'600)         (B*S*2H)
    //   hT   : [15'769'600, 15'802'368)        (B*H)
    //   ut2  : [15'802'368, 15'826'944)        (12 slices x 8 chunks x 256)
    //   xp   : [15'826'944, 55'148'544)        (2*B*S*192) = 157 MB
    float* x    = ws;
    float* mask = ws + 2560000;
    float* out  = ws + 2662400;
    float* hT   = ws + 15769600;
    float* ut2  = ws + 15802368;
    float* xp   = ws + 15826944;

    emb_mean_kernel<<<EMB_BLOCKS + RPK_BLOCKS, 256, 0, stream>>>(
        ids, emb, U_f, U_b, x, mask, ut2);
    xproj_kernel<<<(BATCH * SEQ) / 64, 384, 0, stream>>>(
        x, W_f, b_f, W_b, b_b, xp);
    gru_kernel<<<1024, 384, 0, stream>>>(xp, mask, b_f, b_b, ut2, out, hT);
    attn_kernel<<<BATCH, 256, 0, stream>>>(out, mask, hT, W_k, b_k,
                                           W_q, b_q, W_e, b_e, (float*)d_out);
}